// Round 1
// baseline (2591.314 us; speedup 1.0000x reference)
//
#include <hip/hip_runtime.h>

#define BB 4
#define CC 64
#define SS 2
#define HCC 32
#define WW 128
#define HH 128
#define AREA_ 16384
#define KDIM 288
#define NSLICE 16
#define WPS (WW/NSLICE)

static __device__ __forceinline__ float warp_rsum(float v){
#pragma unroll
  for (int o=32;o>0;o>>=1) v += __shfl_down(v,o,64);
  return v;
}
static __device__ __forceinline__ float warp_rmax(float v){
#pragma unroll
  for (int o=32;o>0;o>>=1) v = fmaxf(v,__shfl_down(v,o,64));
  return v;
}

// ---------- 64x64 1x1 conv (used for trans and out convs) ----------
__global__ __launch_bounds__(256) void conv64_kernel(const float* __restrict__ in,
    const float* __restrict__ wmat, float* __restrict__ out){
  int blk = blockIdx.x;
  int b = blk >> 7;
  int p0 = (blk & 127) << 7;
  __shared__ float tile[64][128];
  const float* inb = in + (size_t)b*CC*AREA_;
  for (int idx = threadIdx.x; idx < 64*128; idx += 256){
    int c = idx >> 7, pp = idx & 127;
    tile[c][pp] = inb[(size_t)c*AREA_ + p0 + pp];
  }
  __syncthreads();
  int pp = threadIdx.x & 127;
  int og = threadIdx.x >> 7;
  float acc[32];
#pragma unroll
  for (int i=0;i<32;i++) acc[i]=0.f;
  for (int c=0;c<64;c++){
    float v = tile[c][pp];
#pragma unroll
    for (int i=0;i<32;i++) acc[i] = fmaf(v, wmat[(og+2*i)*64 + c], acc[i]);
  }
  float* ob = out + (size_t)b*CC*AREA_ + p0 + pp;
#pragma unroll
  for (int i=0;i<32;i++) ob[(size_t)(og+2*i)*AREA_] = acc[i];
}

// ---------- BN stats (per-channel mean/var over B,W,H) -> scale/bias ----------
__global__ __launch_bounds__(256) void bn_stats_kernel(const float* __restrict__ src,
    const float* __restrict__ gam, const float* __restrict__ bet, float* __restrict__ sb){
  int c = blockIdx.x;
  float s1=0.f, s2=0.f;
  for (int b=0;b<BB;b++){
    const float* p = src + ((size_t)b*CC + c)*AREA_;
    for (int i=threadIdx.x;i<AREA_;i+=256){ float v=p[i]; s1+=v; s2+=v*v; }
  }
  __shared__ float r1[4], r2[4];
  float w1 = warp_rsum(s1), w2 = warp_rsum(s2);
  int lane = threadIdx.x & 63, wid = threadIdx.x >> 6;
  if (lane==0){ r1[wid]=w1; r2[wid]=w2; }
  __syncthreads();
  if (threadIdx.x==0){
    float a=r1[0]+r1[1]+r1[2]+r1[3];
    float q=r2[0]+r2[1]+r2[2]+r2[3];
    const float N = (float)(BB*AREA_);
    float m = a/N;
    float var = q/N - m*m;
    float sc = gam[c]*rsqrtf(var + 1e-5f);
    sb[c] = sc;
    sb[64+c] = bet[c] - m*sc;
  }
}

__global__ __launch_bounds__(256) void bn_apply_relu_kernel(const float* __restrict__ src,
    const float* __restrict__ sb, float* __restrict__ dst){
  size_t i = (size_t)blockIdx.x*256 + threadIdx.x;
  int c = (int)((i >> 14) & 63);
  float v = fmaf(src[i], sb[c], sb[64+c]);
  dst[i] = v > 0.f ? v : 0.f;
}

// ---------- query conv (32x32 per s) ----------
__global__ __launch_bounds__(256) void qq_kernel(const float* __restrict__ y,
    const float* __restrict__ qw, float* __restrict__ qq){
  int blk = blockIdx.x;
  int p0 = (blk & 127) << 7;
  int s = (blk >> 7) & 1;
  int b = blk >> 8;
  __shared__ float tile[32][128];
  const float* yb = y + ((size_t)b*CC + s*HCC)*AREA_;
  for (int idx=threadIdx.x; idx<32*128; idx+=256){
    int c=idx>>7, pp=idx&127;
    tile[c][pp] = yb[(size_t)c*AREA_ + p0 + pp];
  }
  __syncthreads();
  int pp = threadIdx.x & 127, og = threadIdx.x >> 7;
  const float* qws = qw + s*HCC*HCC;
  float acc[16];
#pragma unroll
  for (int i=0;i<16;i++) acc[i]=0.f;
  for (int c=0;c<32;c++){
    float v = tile[c][pp];
#pragma unroll
    for (int i=0;i<16;i++) acc[i] = fmaf(v, qws[(og+2*i)*32 + c], acc[i]);
  }
  float* ob = qq + ((size_t)(b*SS+s)*HCC)*AREA_ + p0 + pp;
#pragma unroll
  for (int i=0;i<16;i++) ob[(size_t)(og+2*i)*AREA_] = acc[i];
}

// ---------- Gram matrix P = U * U^T, U = [sur(256); center(32); qq(32)] ----------
__device__ __forceinline__ float u_value(const float* __restrict__ yb,
    const float* __restrict__ qqb, int g, int w, int h, int dil){
  if (g >= 288) return qqb[(size_t)(g-288)*AREA_ + w*HH + h];
  if (g >= 256) return yb[(size_t)(g-256)*AREA_ + w*HH + h];
  const int offy[8] = {-1,-1,-1,0,1,1,1,0};
  const int offx[8] = {-1,0,1,1,1,0,-1,-1};
  int l = g >> 5, ch = g & 31;
  float cv = yb[(size_t)ch*AREA_ + w*HH + h];
  int wy = w + offy[l]*dil, hx = h + offx[l]*dil;
  float nv = (wy>=0 && wy<WW && hx>=0 && hx<HH) ? yb[(size_t)ch*AREA_ + wy*HH + hx] : 0.f;
  return cv - nv;
}

__global__ __launch_bounds__(64) void gram_kernel(const float* __restrict__ y,
    const float* __restrict__ qq, float* __restrict__ P){
  const int PI[15] = {0,0,0,0,0,1,1,1,1,2,2,2,3,3,4};
  const int PJ[15] = {0,1,2,3,4,1,2,3,4,2,3,4,3,4,4};
  int I = PI[blockIdx.x], J = PJ[blockIdx.x];
  int slice = blockIdx.y;
  int bs = blockIdx.z;
  int s = bs & 1;
  int b = bs >> 1;
  int dil = 1 + s;
  const float* yb = y + ((size_t)b*CC + s*HCC)*AREA_;
  const float* qqb = qq + (size_t)bs*HCC*AREA_;
  __shared__ __align__(16) float As[64][68];
  __shared__ __align__(16) float Bs[64][68];
  float acc[8][8];
#pragma unroll
  for (int i=0;i<8;i++)
#pragma unroll
    for (int j=0;j<8;j++) acc[i][j]=0.f;
  int tr = threadIdx.x >> 3, tc = threadIdx.x & 7;
  for (int w = slice*WPS; w < slice*WPS + WPS; ++w){
    for (int h0 = 0; h0 < HH; h0 += 64){
      for (int r=0;r<64;r++)
        As[r][threadIdx.x] = u_value(yb,qqb, I*64+r, w, h0+(int)threadIdx.x, dil);
      if (J != I){
        for (int r=0;r<64;r++)
          Bs[r][threadIdx.x] = u_value(yb,qqb, J*64+r, w, h0+(int)threadIdx.x, dil);
      }
      __syncthreads();
      const float (*Bp)[68] = (J!=I) ? Bs : As;
      for (int h=0; h<64; h+=4){
        float4 av[8], bv[8];
#pragma unroll
        for (int i=0;i<8;i++) av[i] = *(const float4*)&As[tr + 8*i][h];
#pragma unroll
        for (int j=0;j<8;j++) bv[j] = *(const float4*)&Bp[tc + 8*j][h];
#pragma unroll
        for (int i=0;i<8;i++)
#pragma unroll
          for (int j=0;j<8;j++){
            acc[i][j] = fmaf(av[i].x, bv[j].x, acc[i][j]);
            acc[i][j] = fmaf(av[i].y, bv[j].y, acc[i][j]);
            acc[i][j] = fmaf(av[i].z, bv[j].z, acc[i][j]);
            acc[i][j] = fmaf(av[i].w, bv[j].w, acc[i][j]);
          }
      }
      __syncthreads();
    }
  }
  float* Pb = P + (size_t)bs*320*320;
#pragma unroll
  for (int i=0;i<8;i++)
#pragma unroll
    for (int j=0;j<8;j++)
      atomicAdd(&Pb[(size_t)(I*64 + tr + 8*i)*320 + (J*64 + tc + 8*j)], acc[i][j]);
}

__global__ __launch_bounds__(256) void symmetrize_kernel(float* __restrict__ P){
  int idx = blockIdx.x*256 + threadIdx.x;
  if (idx >= 320*320) return;
  int r = idx/320, c = idx - r*320;
  float* Pb = P + (size_t)blockIdx.y*320*320;
  if (r > c) Pb[idx] = Pb[(size_t)c*320 + r];
}

// ---------- V = P[0:288,0:288] * Kw^T (for key norms) ----------
__global__ __launch_bounds__(256) void vmat_kernel(const float* __restrict__ P,
    const float* __restrict__ kw, float* __restrict__ V){
  int j = blockIdx.x;       // 0..287
  int bs = blockIdx.y;      // 0..7
  int s = bs & 1;
  __shared__ float prow[288];
  const float* Pb = P + (size_t)bs*320*320 + (size_t)j*320;
  for (int i=threadIdx.x;i<288;i+=256) prow[i]=Pb[i];
  __syncthreads();
  const float* kws = kw + (size_t)s*KDIM*KDIM + (size_t)threadIdx.x*KDIM;
  float acc=0.f;
  for (int jp=0;jp<288;jp++) acc = fmaf(prow[jp], kws[jp], acc);
  V[((size_t)bs*KDIM + j)*256 + threadIdx.x] = acc;
}

// ---------- norms + w + instance-norm + softmax -> sw (B,S,32,256) ----------
__global__ __launch_bounds__(256) void softmax_kernel(const float* __restrict__ P,
    const float* __restrict__ V, const float* __restrict__ kw, float* __restrict__ sw){
  int bs = blockIdx.x; int s = bs & 1;
  const float* Pb = P + (size_t)bs*320*320;
  const float* kws = kw + (size_t)s*KDIM*KDIM;
  __shared__ float wbuf[32*256];
  __shared__ float knorm[256];
  __shared__ float qnorm[32];
  __shared__ float sred[4];
  int k = threadIdx.x;
  {
    const float* Vb = V + (size_t)bs*KDIM*256;
    float acc=0.f;
    for (int j=0;j<288;j++) acc = fmaf(kws[(size_t)k*KDIM+j], Vb[(size_t)j*256+k], acc);
    knorm[k] = fmaxf(sqrtf(fmaxf(acc,0.f)), 1e-12f);
  }
  if (k < 32) qnorm[k] = fmaxf(sqrtf(fmaxf(Pb[(size_t)(288+k)*320 + 288+k], 0.f)), 1e-12f);
  __syncthreads();
  float s1=0.f, s2=0.f;
  for (int c=0;c<32;c++){
    const float* prow = Pb + (size_t)(288+c)*320;
    float acc=0.f;
    for (int j=0;j<288;j++) acc = fmaf(prow[j], kws[(size_t)k*KDIM+j], acc);
    float wv = acc / (qnorm[c]*knorm[k]*128.0f);
    wbuf[c*256+k] = wv;
    s1 += wv; s2 += wv*wv;
  }
  int lane = k & 63, wid = k >> 6;
  float w1 = warp_rsum(s1);
  if (lane==0) sred[wid]=w1;
  __syncthreads();
  float S1 = sred[0]+sred[1]+sred[2]+sred[3];
  __syncthreads();
  float w2 = warp_rsum(s2);
  if (lane==0) sred[wid]=w2;
  __syncthreads();
  float S2 = sred[0]+sred[1]+sred[2]+sred[3];
  __syncthreads();
  const float N = 8192.0f;
  float m = S1/N;
  float var = S2/N - m*m;
  float rs = rsqrtf(var + 1e-5f);
  for (int c=0;c<32;c++){
    float v = (wbuf[c*256+k]-m)*rs;
    float mx = warp_rmax(v);
    if (lane==0) sred[wid]=mx;
    __syncthreads();
    float MX = fmaxf(fmaxf(sred[0],sred[1]),fmaxf(sred[2],sred[3]));
    __syncthreads();
    float e = expf(v - MX);
    float es = warp_rsum(e);
    if (lane==0) sred[wid]=es;
    __syncthreads();
    float ES = sred[0]+sred[1]+sred[2]+sred[3];
    __syncthreads();
    sw[((size_t)bs*32 + c)*256 + k] = e/ES;
  }
}

// ---------- tap coefficients from sw: T[bs][c][t=0..8][ch] ----------
__global__ __launch_bounds__(256) void tsw_kernel(const float* __restrict__ sw, float* __restrict__ tsw){
  int idx = blockIdx.x*256 + threadIdx.x;
  if (idx >= BB*SS*32*9*32) return;
  int ch = idx & 31;
  int t = (idx >> 5) % 9;
  int c = (idx / 288) & 31;
  int bs = idx / 9216;
  const float* swb = sw + ((size_t)bs*32 + c)*256;
  float v;
  if (t==0){ v=0.f; for (int l=0;l<8;l++) v += swb[l*32+ch]; }
  else v = -swb[(t-1)*32 + ch];
  tsw[idx] = v;
}

// ---------- apply attention as 9-tap stencil -> outs (B,S,32,AREA) ----------
__global__ __launch_bounds__(256) void attn_apply_kernel(const float* __restrict__ y,
    const float* __restrict__ tsw, float* __restrict__ outs){
  int blk = blockIdx.x;
  int w = blk & 127;
  int s = (blk >> 7) & 1;
  int b = blk >> 8;
  int dil = 1 + s;
  __shared__ float T[9216];
  const float* tb = tsw + (size_t)(b*SS+s)*9216;
  for (int i=threadIdx.x;i<9216;i+=256) T[i]=tb[i];
  __syncthreads();
  int h = threadIdx.x & 127, cg = threadIdx.x >> 7;
  const float* yb = y + ((size_t)b*CC + s*HCC)*AREA_;
  float acc[16];
#pragma unroll
  for (int i=0;i<16;i++) acc[i]=0.f;
  const int offy[9]={0,-1,-1,-1,0,1,1,1,0};
  const int offx[9]={0,-1,0,1,1,1,0,-1,-1};
  for (int t=0;t<9;t++){
    int wy = w + offy[t]*dil;
    if (wy < 0 || wy >= WW) continue;
    int hx = h + offx[t]*dil;
    bool okh = (hx>=0 && hx<HH);
    const float* ycol = yb + (size_t)wy*HH;
    for (int ch=0;ch<32;ch++){
      float v = okh ? ycol[(size_t)ch*AREA_ + hx] : 0.f;
      const float* Tp = &T[(cg*16)*288 + t*32 + ch];
#pragma unroll
      for (int i=0;i<16;i++) acc[i] = fmaf(Tp[i*288], v, acc[i]);
    }
  }
  float* ob = outs + ((size_t)(b*SS+s)*HCC + cg*16)*AREA_ + (size_t)w*HH + h;
#pragma unroll
  for (int i=0;i<16;i++) ob[(size_t)i*AREA_] = acc[i];
}

extern "C" void kernel_launch(void* const* d_in, const int* in_sizes, int n_in,
                              void* d_out, int out_size, void* d_ws, size_t ws_size,
                              hipStream_t stream){
  const float* x   = (const float*)d_in[0];
  const float* tw  = (const float*)d_in[1];
  const float* g1  = (const float*)d_in[2];
  const float* b1  = (const float*)d_in[3];
  const float* qw  = (const float*)d_in[4];
  const float* kw  = (const float*)d_in[5];
  const float* ow  = (const float*)d_in[6];
  const float* g2  = (const float*)d_in[7];
  const float* b2  = (const float*)d_in[8];
  float* out = (float*)d_out;
  float* ws = (float*)d_ws;

  float* y    = ws;                    // 4,194,304 floats
  float* qqz  = ws + 4194304;          // qq, later reused as z
  float* P    = ws + 8388608;          // 8*320*320 = 819,200
  float* V    = ws + 9207808;          // 8*288*256 = 589,824
  float* swb  = ws + 9797632;          // 8*32*256  = 65,536
  float* tswb = ws + 9863168;          // 8*32*9*32 = 73,728
  float* outs = ws + 9936896;          // 4,194,304
  float* st   = ws + 14131200;         // stats: [0..127] bn1, [128..255] bn2

  hipMemsetAsync(P, 0, (size_t)8*320*320*sizeof(float), stream);

  conv64_kernel<<<512,256,0,stream>>>(x, tw, y);
  bn_stats_kernel<<<64,256,0,stream>>>(y, g1, b1, st);
  bn_apply_relu_kernel<<<16384,256,0,stream>>>(y, st, y);
  qq_kernel<<<1024,256,0,stream>>>(y, qw, qqz);
  gram_kernel<<<dim3(15,NSLICE,8),64,0,stream>>>(y, qqz, P);
  symmetrize_kernel<<<dim3(400,8),256,0,stream>>>(P);
  vmat_kernel<<<dim3(288,8),256,0,stream>>>(P, kw, V);
  softmax_kernel<<<8,256,0,stream>>>(P, V, kw, swb);
  tsw_kernel<<<288,256,0,stream>>>(swb, tswb);
  attn_apply_kernel<<<1024,256,0,stream>>>(y, tswb, outs);
  conv64_kernel<<<512,256,0,stream>>>(outs, ow, qqz);
  bn_stats_kernel<<<64,256,0,stream>>>(qqz, g2, b2, st+128);
  bn_apply_relu_kernel<<<16384,256,0,stream>>>(qqz, st+128, out);
}

// Round 2
// 1199.357 us; speedup vs baseline: 2.1606x; 2.1606x over previous
//
#include <hip/hip_runtime.h>

#define BB 4
#define CC 64
#define SS 2
#define HCC 32
#define WW 128
#define HH 128
#define AREA_ 16384
#define KDIM 288

static __device__ __forceinline__ float warp_rsum(float v){
#pragma unroll
  for (int o=32;o>0;o>>=1) v += __shfl_down(v,o,64);
  return v;
}
static __device__ __forceinline__ float warp_rmax(float v){
#pragma unroll
  for (int o=32;o>0;o>>=1) v = fmaxf(v,__shfl_down(v,o,64));
  return v;
}

// ---------- 64x64 1x1 conv ----------
__global__ __launch_bounds__(256) void conv64_kernel(const float* __restrict__ in,
    const float* __restrict__ wmat, float* __restrict__ out){
  int b = blockIdx.x >> 7;
  int p0 = (blockIdx.x & 127) << 7;
  __shared__ float tile[64][132];
  __shared__ float wsm[64][68];   // transposed [c][o]
  for (int idx = threadIdx.x; idx < 4096; idx += 256){
    int c = idx & 63, o = idx >> 6;
    wsm[c][o] = wmat[o*64 + c];
  }
  const float* inb = in + (size_t)b*CC*AREA_ + p0;
  for (int idx = threadIdx.x; idx < 8192; idx += 256){
    int c = idx >> 7, pp = idx & 127;
    tile[c][pp] = inb[(size_t)c*AREA_ + pp];
  }
  __syncthreads();
  int px = (threadIdx.x & 31) * 4;
  int og = threadIdx.x >> 5;      // 0..7 -> outputs og*8..og*8+7
  float4 acc[8];
#pragma unroll
  for (int i=0;i<8;i++) acc[i] = make_float4(0.f,0.f,0.f,0.f);
  for (int c=0;c<64;c++){
    float4 v  = *(const float4*)&tile[c][px];
    float4 w0 = *(const float4*)&wsm[c][og*8];
    float4 w1 = *(const float4*)&wsm[c][og*8+4];
    float wv[8] = {w0.x,w0.y,w0.z,w0.w,w1.x,w1.y,w1.z,w1.w};
#pragma unroll
    for (int i=0;i<8;i++){
      acc[i].x = fmaf(wv[i], v.x, acc[i].x);
      acc[i].y = fmaf(wv[i], v.y, acc[i].y);
      acc[i].z = fmaf(wv[i], v.z, acc[i].z);
      acc[i].w = fmaf(wv[i], v.w, acc[i].w);
    }
  }
  float* ob = out + (size_t)b*CC*AREA_ + p0 + px;
#pragma unroll
  for (int i=0;i<8;i++)
    *(float4*)&ob[(size_t)(og*8+i)*AREA_] = acc[i];
}

// ---------- BN partial stats ----------
__global__ __launch_bounds__(256) void bn_part_kernel(const float* __restrict__ src,
    float* __restrict__ part){
  int c = blockIdx.x, chunk = blockIdx.y;
  float s1=0.f, s2=0.f;
  for (int b=0;b<BB;b++){
    const float* p = src + ((size_t)b*CC + c)*AREA_ + chunk*2048;
    for (int i=threadIdx.x;i<2048;i+=256){ float v=p[i]; s1+=v; s2+=v*v; }
  }
  __shared__ float red[8];
  float w1 = warp_rsum(s1), w2 = warp_rsum(s2);
  int lane = threadIdx.x & 63, wid = threadIdx.x >> 6;
  if (lane==0){ red[wid]=w1; red[4+wid]=w2; }
  __syncthreads();
  if (threadIdx.x==0){
    atomicAdd(&part[c], red[0]+red[1]+red[2]+red[3]);
    atomicAdd(&part[64+c], red[4]+red[5]+red[6]+red[7]);
  }
}

__global__ void bn_fin_kernel(const float* __restrict__ part, const float* __restrict__ gam,
    const float* __restrict__ bet, float* __restrict__ sb){
  int c = threadIdx.x;
  const float N = (float)(BB*AREA_);
  float m = part[c]/N;
  float var = part[64+c]/N - m*m;
  float sc = gam[c]*rsqrtf(var + 1e-5f);
  sb[c] = sc;
  sb[64+c] = bet[c] - m*sc;
}

__global__ __launch_bounds__(256) void bn_apply_relu_kernel(const float* __restrict__ src,
    const float* __restrict__ sb, float* __restrict__ dst){
  size_t i = (size_t)blockIdx.x*256 + threadIdx.x;
  int c = (int)((i >> 14) & 63);
  float v = fmaf(src[i], sb[c], sb[64+c]);
  dst[i] = v > 0.f ? v : 0.f;
}

// ---------- query conv ----------
__global__ __launch_bounds__(256) void qq_kernel(const float* __restrict__ y,
    const float* __restrict__ qw, float* __restrict__ qq){
  int blk = blockIdx.x;
  int p0 = (blk & 127) << 7;
  int s = (blk >> 7) & 1;
  int b = blk >> 8;
  __shared__ float tile[32][132];
  __shared__ float wsm[32][36];
  const float* qws = qw + s*HCC*HCC;
  for (int idx=threadIdx.x; idx<1024; idx+=256){
    int c = idx & 31, o = idx >> 5;
    wsm[c][o] = qws[o*32 + c];
  }
  const float* yb = y + ((size_t)b*CC + s*HCC)*AREA_ + p0;
  for (int idx=threadIdx.x; idx<4096; idx+=256){
    int c=idx>>7, pp=idx&127;
    tile[c][pp] = yb[(size_t)c*AREA_ + pp];
  }
  __syncthreads();
  int px = (threadIdx.x & 31) * 4;
  int og = threadIdx.x >> 5;   // outputs og*4..og*4+3
  float4 acc[4];
#pragma unroll
  for (int i=0;i<4;i++) acc[i] = make_float4(0.f,0.f,0.f,0.f);
  for (int c=0;c<32;c++){
    float4 v  = *(const float4*)&tile[c][px];
    float4 w0 = *(const float4*)&wsm[c][og*4];
    float wv[4] = {w0.x,w0.y,w0.z,w0.w};
#pragma unroll
    for (int i=0;i<4;i++){
      acc[i].x = fmaf(wv[i], v.x, acc[i].x);
      acc[i].y = fmaf(wv[i], v.y, acc[i].y);
      acc[i].z = fmaf(wv[i], v.z, acc[i].z);
      acc[i].w = fmaf(wv[i], v.w, acc[i].w);
    }
  }
  float* ob = qq + ((size_t)(b*SS+s)*HCC)*AREA_ + p0 + px;
#pragma unroll
  for (int i=0;i<4;i++)
    *(float4*)&ob[(size_t)(og*4+i)*AREA_] = acc[i];
}

// ---------- Gram staging ----------
__device__ __forceinline__ void gram_stage(float (*S)[36], const float* __restrict__ yb,
    const float* __restrict__ qqb, int panel, int w, int h0, int dil, int tid, int mmax){
  int k = tid & 31, h = h0 + k;
  int r0 = tid >> 5;
  if (panel < 2){
#pragma unroll
    for (int m=0;m<16;m++){
      int r = r0 + 8*m;
      int g = panel*128 + r;
      int l = g >> 5, ch = g & 31;
      int oy = ((0x6A40 >> (2*l)) & 3) - 1;
      int ox = ((0x6A4  >> (2*l)) & 3) - 1;
      float cv = yb[(size_t)ch*AREA_ + w*HH + h];
      int wy = w + oy*dil, hx = h + ox*dil;
      float nv = (wy>=0 && wy<WW && hx>=0 && hx<HH) ? yb[(size_t)ch*AREA_ + wy*HH + hx] : 0.f;
      S[r][k] = cv - nv;
    }
  } else {
    for (int m=0;m<mmax;m++){
      int r = r0 + 8*m;
      float v = 0.f;
      if (r < 32) v = yb[(size_t)r*AREA_ + w*HH + h];
      else if (r < 64) v = qqb[(size_t)(r-32)*AREA_ + w*HH + h];
      S[r][k] = v;
    }
  }
}

// ---------- Gram full tiles: (0,0),(0,1),(1,1) 128x128 ----------
__global__ __launch_bounds__(256,2) void gram_full_kernel(const float* __restrict__ y,
    const float* __restrict__ qq, float* __restrict__ P){
  const int TI[3] = {0,0,1};
  const int TJ[3] = {0,1,1};
  int I = TI[blockIdx.x], J = TJ[blockIdx.x];
  int slice = blockIdx.y, bs = blockIdx.z;
  int s = bs & 1, b = bs >> 1, dil = 1 + s;
  const float* yb  = y + ((size_t)b*CC + s*HCC)*AREA_;
  const float* qqb = qq + (size_t)bs*HCC*AREA_;
  __shared__ float As[128][36];
  __shared__ float Bs[128][36];
  int tid = threadIdx.x;
  int lane = tid & 63, wid = tid >> 6;
  int rgrp = ((wid&1)<<3) | (lane>>3);
  int cgrp = ((wid>>1)<<3) | (lane&7);
  float acc[8][8];
#pragma unroll
  for (int i=0;i<8;i++)
#pragma unroll
    for (int j=0;j<8;j++) acc[i][j]=0.f;
  for (int w = slice*8; w < slice*8+8; ++w){
    for (int h0 = 0; h0 < 128; h0 += 32){
      gram_stage(As, yb, qqb, I, w, h0, dil, tid, 16);
      if (J != I) gram_stage(Bs, yb, qqb, J, w, h0, dil, tid, 16);
      __syncthreads();
      float (*Bp)[36] = (J != I) ? Bs : As;
#pragma unroll
      for (int k=0;k<32;k+=4){
        float4 av[8], bv[8];
#pragma unroll
        for (int i=0;i<8;i++) av[i] = *(const float4*)&As[rgrp+16*i][k];
#pragma unroll
        for (int j=0;j<8;j++) bv[j] = *(const float4*)&Bp[cgrp+16*j][k];
#pragma unroll
        for (int i=0;i<8;i++)
#pragma unroll
          for (int j=0;j<8;j++){
            acc[i][j] = fmaf(av[i].x, bv[j].x, acc[i][j]);
            acc[i][j] = fmaf(av[i].y, bv[j].y, acc[i][j]);
            acc[i][j] = fmaf(av[i].z, bv[j].z, acc[i][j]);
            acc[i][j] = fmaf(av[i].w, bv[j].w, acc[i][j]);
          }
      }
      __syncthreads();
    }
  }
  float* Pb = P + (size_t)bs*320*320;
#pragma unroll
  for (int i=0;i<8;i++)
#pragma unroll
    for (int j=0;j<8;j++)
      atomicAdd(&Pb[(size_t)(I*128+rgrp+16*i)*320 + (J*128+cgrp+16*j)], acc[i][j]);
}

// ---------- Gram row-panel-2 tiles: rows 256-319 x col panel cp (64x128) ----------
__global__ __launch_bounds__(256,2) void gram_row2_kernel(const float* __restrict__ y,
    const float* __restrict__ qq, float* __restrict__ P){
  int cp = blockIdx.x;           // 0,1,2
  int slice = blockIdx.y, bs = blockIdx.z;
  int s = bs & 1, b = bs >> 1, dil = 1 + s;
  const float* yb  = y + ((size_t)b*CC + s*HCC)*AREA_;
  const float* qqb = qq + (size_t)bs*HCC*AREA_;
  __shared__ float As[64][36];
  __shared__ float Bs[128][36];
  int tid = threadIdx.x;
  int lane = tid & 63, wid = tid >> 6;
  int rgrp = ((wid&1)<<3) | (lane>>3);
  int cgrp = ((wid>>1)<<3) | (lane&7);
  float acc[4][8];
#pragma unroll
  for (int i=0;i<4;i++)
#pragma unroll
    for (int j=0;j<8;j++) acc[i][j]=0.f;
  for (int w = slice*8; w < slice*8+8; ++w){
    for (int h0 = 0; h0 < 128; h0 += 32){
      gram_stage(As, yb, qqb, 2, w, h0, dil, tid, 8);
      gram_stage(Bs, yb, qqb, cp, w, h0, dil, tid, 16);
      __syncthreads();
#pragma unroll
      for (int k=0;k<32;k+=4){
        float4 av[4], bv[8];
#pragma unroll
        for (int i=0;i<4;i++) av[i] = *(const float4*)&As[rgrp+16*i][k];
#pragma unroll
        for (int j=0;j<8;j++) bv[j] = *(const float4*)&Bs[cgrp+16*j][k];
#pragma unroll
        for (int i=0;i<4;i++)
#pragma unroll
          for (int j=0;j<8;j++){
            acc[i][j] = fmaf(av[i].x, bv[j].x, acc[i][j]);
            acc[i][j] = fmaf(av[i].y, bv[j].y, acc[i][j]);
            acc[i][j] = fmaf(av[i].z, bv[j].z, acc[i][j]);
            acc[i][j] = fmaf(av[i].w, bv[j].w, acc[i][j]);
          }
      }
      __syncthreads();
    }
  }
  float* Pb = P + (size_t)bs*320*320;
#pragma unroll
  for (int i=0;i<4;i++)
#pragma unroll
    for (int j=0;j<8;j++){
      int gr = 256 + rgrp + 16*i;
      int gc = cp*128 + cgrp + 16*j;
      if (gc < 320) atomicAdd(&Pb[(size_t)gc*320 + gr], acc[i][j]);  // transposed -> upper triangle
    }
}

__global__ __launch_bounds__(256) void symmetrize_kernel(float* __restrict__ P){
  int idx = blockIdx.x*256 + threadIdx.x;
  if (idx >= 320*320) return;
  int r = idx/320, c = idx - r*320;
  float* Pb = P + (size_t)blockIdx.y*320*320;
  if (r > c) Pb[idx] = Pb[(size_t)c*320 + r];
}

// ---------- kw transpose: kwT[s][j][k] = kw[s][k][j] ----------
__global__ __launch_bounds__(256) void kwT_kernel(const float* __restrict__ kw, float* __restrict__ kwT){
  int idx = blockIdx.x*256 + threadIdx.x;
  if (idx >= 2*KDIM*KDIM) return;
  int s = idx / (KDIM*KDIM);
  int r = idx - s*KDIM*KDIM;
  int k = r / KDIM, j = r - k*KDIM;
  kwT[(size_t)s*KDIM*KDIM + (size_t)j*KDIM + k] = kw[idx];
}

// ---------- V[j][k] = sum_jp P[j][jp] * kw[k][jp] ----------
__global__ __launch_bounds__(256) void vmat_kernel(const float* __restrict__ P,
    const float* __restrict__ kwT, float* __restrict__ V){
  int j = blockIdx.x, bs = blockIdx.y;
  int s = bs & 1;
  __shared__ float prow[KDIM];
  const float* Pb = P + (size_t)bs*320*320 + (size_t)j*320;
  for (int i=threadIdx.x;i<KDIM;i+=256) prow[i]=Pb[i];
  __syncthreads();
  const float* kt = kwT + (size_t)s*KDIM*KDIM;
  int k = threadIdx.x;   // 0..255
  float acc=0.f;
  for (int jp=0;jp<KDIM;jp++) acc = fmaf(prow[jp], kt[(size_t)jp*KDIM + k], acc);
  V[((size_t)bs*KDIM + j)*256 + k] = acc;
}

// ---------- norms (reciprocal) ----------
__global__ void knorm_kernel(const float* __restrict__ P, const float* __restrict__ V,
    const float* __restrict__ kwT, float* __restrict__ nrm){
  int bs = blockIdx.x, s = bs & 1;
  int k = threadIdx.x;  // 0..255
  const float* Vb = V + (size_t)bs*KDIM*256;
  const float* kt = kwT + (size_t)s*KDIM*KDIM;
  float acc=0.f;
  for (int j=0;j<KDIM;j++) acc = fmaf(kt[(size_t)j*KDIM + k], Vb[(size_t)j*256 + k], acc);
  nrm[bs*KDIM + k] = 1.f/fmaxf(sqrtf(fmaxf(acc,0.f)), 1e-12f);
  if (k < 32){
    const float* Pb = P + (size_t)bs*320*320;
    float q = Pb[(size_t)(288+k)*320 + 288+k];
    nrm[bs*KDIM + 256 + k] = 1.f/fmaxf(sqrtf(fmaxf(q,0.f)), 1e-12f);
  }
}

// ---------- w row + partial inorm stats ----------
__global__ __launch_bounds__(256) void wmat_kernel(const float* __restrict__ P,
    const float* __restrict__ kwT, const float* __restrict__ nrm,
    float* __restrict__ wbuf, float* __restrict__ wstats){
  int bs = blockIdx.x >> 5, c = blockIdx.x & 31;
  int s = bs & 1;
  __shared__ float prow[KDIM];
  const float* Pb = P + (size_t)bs*320*320 + (size_t)(288+c)*320;
  for (int i=threadIdx.x;i<KDIM;i+=256) prow[i]=Pb[i];
  __syncthreads();
  const float* kt = kwT + (size_t)s*KDIM*KDIM;
  int k = threadIdx.x;
  float acc=0.f;
  for (int j=0;j<KDIM;j++) acc = fmaf(prow[j], kt[(size_t)j*KDIM + k], acc);
  float wv = acc * nrm[bs*KDIM + 256 + c] * nrm[bs*KDIM + k] * (1.f/128.f);
  wbuf[((size_t)bs*32 + c)*256 + k] = wv;
  __shared__ float red[8];
  float r1 = warp_rsum(wv), r2 = warp_rsum(wv*wv);
  int lane = threadIdx.x & 63, wid = threadIdx.x >> 6;
  if (lane==0){ red[wid]=r1; red[4+wid]=r2; }
  __syncthreads();
  if (threadIdx.x==0){
    atomicAdd(&wstats[bs*2],   red[0]+red[1]+red[2]+red[3]);
    atomicAdd(&wstats[bs*2+1], red[4]+red[5]+red[6]+red[7]);
  }
}

// ---------- inorm + softmax ----------
__global__ __launch_bounds__(256) void smx_kernel(const float* __restrict__ wbuf,
    const float* __restrict__ wstats, float* __restrict__ sw){
  int bs = blockIdx.x >> 5, c = blockIdx.x & 31;
  float s1 = wstats[bs*2], s2 = wstats[bs*2+1];
  const float N = 8192.f;
  float m = s1/N, var = s2/N - m*m;
  float rs = rsqrtf(var + 1e-5f);
  int k = threadIdx.x;
  float v = (wbuf[((size_t)bs*32 + c)*256 + k] - m)*rs;
  __shared__ float red[4];
  float mx = warp_rmax(v);
  int lane = k & 63, wid = k >> 6;
  if (lane==0) red[wid]=mx;
  __syncthreads();
  float MX = fmaxf(fmaxf(red[0],red[1]),fmaxf(red[2],red[3]));
  __syncthreads();
  float e = expf(v - MX);
  float es = warp_rsum(e);
  if (lane==0) red[wid]=es;
  __syncthreads();
  float ES = red[0]+red[1]+red[2]+red[3];
  sw[((size_t)bs*32 + c)*256 + k] = e/ES;
}

// ---------- tap coefficients ----------
__global__ __launch_bounds__(256) void tsw_kernel(const float* __restrict__ sw, float* __restrict__ tsw){
  int idx = blockIdx.x*256 + threadIdx.x;
  if (idx >= BB*SS*32*9*32) return;
  int ch = idx & 31;
  int t = (idx >> 5) % 9;
  int c = (idx / 288) & 31;
  int bs = idx / 9216;
  const float* swb = sw + ((size_t)bs*32 + c)*256;
  float v;
  if (t==0){ v=0.f; for (int l=0;l<8;l++) v += swb[l*32+ch]; }
  else v = -swb[(t-1)*32 + ch];
  tsw[idx] = v;
}

// ---------- attention as 9-tap stencil ----------
__global__ __launch_bounds__(256) void attn_apply_kernel(const float* __restrict__ y,
    const float* __restrict__ tsw, float* __restrict__ outs){
  int blk = blockIdx.x;
  int w = blk & 127;
  int s = (blk >> 7) & 1;
  int b = blk >> 8;
  int dil = 1 + s;
  __shared__ float T[9216];
  const float* tb = tsw + (size_t)(b*SS+s)*9216;
  for (int i=threadIdx.x;i<9216;i+=256) T[i]=tb[i];
  __syncthreads();
  int h = threadIdx.x & 127, cg = threadIdx.x >> 7;
  const float* yb = y + ((size_t)b*CC + s*HCC)*AREA_;
  float acc[16];
#pragma unroll
  for (int i=0;i<16;i++) acc[i]=0.f;
  const int offy[9]={0,-1,-1,-1,0,1,1,1,0};
  const int offx[9]={0,-1,0,1,1,1,0,-1,-1};
#pragma unroll
  for (int t=0;t<9;t++){
    int wy = w + offy[t]*dil;
    if (wy < 0 || wy >= WW) continue;
    int hx = h + offx[t]*dil;
    bool okh = (hx>=0 && hx<HH);
    const float* ycol = yb + (size_t)wy*HH + hx;
    for (int c4=0;c4<8;c4++){
      float v0 = okh ? ycol[(size_t)(c4*4+0)*AREA_] : 0.f;
      float v1 = okh ? ycol[(size_t)(c4*4+1)*AREA_] : 0.f;
      float v2 = okh ? ycol[(size_t)(c4*4+2)*AREA_] : 0.f;
      float v3 = okh ? ycol[(size_t)(c4*4+3)*AREA_] : 0.f;
      const float* Tp = &T[(cg*16)*288 + t*32 + c4*4];
#pragma unroll
      for (int i=0;i<16;i++){
        float4 tw = *(const float4*)&Tp[(size_t)i*288];
        acc[i] = fmaf(tw.x, v0, fmaf(tw.y, v1, fmaf(tw.z, v2, fmaf(tw.w, v3, acc[i]))));
      }
    }
  }
  float* ob = outs + ((size_t)(b*SS+s)*HCC + cg*16)*AREA_ + (size_t)w*HH + h;
#pragma unroll
  for (int i=0;i<16;i++) ob[(size_t)i*AREA_] = acc[i];
}

extern "C" void kernel_launch(void* const* d_in, const int* in_sizes, int n_in,
                              void* d_out, int out_size, void* d_ws, size_t ws_size,
                              hipStream_t stream){
  const float* x   = (const float*)d_in[0];
  const float* tw  = (const float*)d_in[1];
  const float* g1  = (const float*)d_in[2];
  const float* b1  = (const float*)d_in[3];
  const float* qw  = (const float*)d_in[4];
  const float* kw  = (const float*)d_in[5];
  const float* ow  = (const float*)d_in[6];
  const float* g2  = (const float*)d_in[7];
  const float* b2  = (const float*)d_in[8];
  float* out = (float*)d_out;
  float* ws = (float*)d_ws;

  float* y     = ws;                         // 4,194,304
  float* Abuf  = ws + 4194304;               // qq during phase 1; kwT/V/wbuf/nrm after gram
  float* qqb   = Abuf;
  float* kwT   = Abuf;
  float* V     = Abuf + 165888;
  float* wbuf  = Abuf + 755712;
  float* nrm   = Abuf + 821248;
  float* P     = ws + 8388608;               // 819,200
  float* stats = ws + 9207808;               // 512: bn1p[0..127] bn2p[128..255] wstats[256..271]
  float* sb    = ws + 9208320;               // sb1@0, sb2@128
  float* swb   = ws + 9208576;               // 65,536
  float* tswb  = ws + 9274112;               // 73,728
  float* outs  = ws + 9347840;               // 4,194,304
  float* wstats = stats + 256;

  hipMemsetAsync(P, 0, (size_t)819712*sizeof(float), stream);

  conv64_kernel<<<512,256,0,stream>>>(x, tw, y);
  bn_part_kernel<<<dim3(64,8),256,0,stream>>>(y, stats);
  bn_fin_kernel<<<1,64,0,stream>>>(stats, g1, b1, sb);
  bn_apply_relu_kernel<<<16384,256,0,stream>>>(y, sb, y);
  qq_kernel<<<1024,256,0,stream>>>(y, qw, qqb);
  gram_full_kernel<<<dim3(3,16,8),256,0,stream>>>(y, qqb, P);
  gram_row2_kernel<<<dim3(3,16,8),256,0,stream>>>(y, qqb, P);
  symmetrize_kernel<<<dim3(400,8),256,0,stream>>>(P);
  kwT_kernel<<<648,256,0,stream>>>(kw, kwT);
  vmat_kernel<<<dim3(288,8),256,0,stream>>>(P, kwT, V);
  knorm_kernel<<<8,256,0,stream>>>(P, V, kwT, nrm);
  wmat_kernel<<<256,256,0,stream>>>(P, kwT, nrm, wbuf, wstats);
  smx_kernel<<<256,256,0,stream>>>(wbuf, wstats, swb);
  tsw_kernel<<<288,256,0,stream>>>(swb, tswb);
  attn_apply_kernel<<<1024,256,0,stream>>>(y, tswb, outs);
  conv64_kernel<<<512,256,0,stream>>>(outs, ow, y);
  bn_part_kernel<<<dim3(64,8),256,0,stream>>>(y, stats+128);
  bn_fin_kernel<<<1,64,0,stream>>>(stats+128, g2, b2, sb+128);
  bn_apply_relu_kernel<<<16384,256,0,stream>>>(y, sb+128, out);
}

// Round 4
// 783.617 us; speedup vs baseline: 3.3069x; 1.5305x over previous
//
#include <hip/hip_runtime.h>

#define BB 4
#define CC 64
#define SS 2
#define HCC 32
#define AREA_ 16384
#define KDIM 288

typedef _Float16 half8 __attribute__((ext_vector_type(8)));
typedef float f32x16 __attribute__((ext_vector_type(16)));

static __device__ __forceinline__ float warp_rsum(float v){
#pragma unroll
  for (int o=32;o>0;o>>=1) v += __shfl_down(v,o,64);
  return v;
}
static __device__ __forceinline__ float warp_rmax(float v){
#pragma unroll
  for (int o=32;o>0;o>>=1) v = fmaxf(v,__shfl_down(v,o,64));
  return v;
}

// ---------- 64x64 1x1 conv ----------
__global__ __launch_bounds__(256) void conv64_kernel(const float* __restrict__ in,
    const float* __restrict__ wmat, float* __restrict__ out){
  int b = blockIdx.x >> 7;
  int p0 = (blockIdx.x & 127) << 7;
  __shared__ float tile[64][132];
  __shared__ float wsm[64][68];
  for (int idx = threadIdx.x; idx < 4096; idx += 256){
    int c = idx & 63, o = idx >> 6;
    wsm[c][o] = wmat[o*64 + c];
  }
  const float* inb = in + (size_t)b*CC*AREA_ + p0;
  for (int idx = threadIdx.x; idx < 8192; idx += 256){
    int c = idx >> 7, pp = idx & 127;
    tile[c][pp] = inb[(size_t)c*AREA_ + pp];
  }
  __syncthreads();
  int px = (threadIdx.x & 31) * 4;
  int og = threadIdx.x >> 5;
  float4 acc[8];
#pragma unroll
  for (int i=0;i<8;i++) acc[i] = make_float4(0.f,0.f,0.f,0.f);
  for (int c=0;c<64;c++){
    float4 v  = *(const float4*)&tile[c][px];
    float4 w0 = *(const float4*)&wsm[c][og*8];
    float4 w1 = *(const float4*)&wsm[c][og*8+4];
    float wv[8] = {w0.x,w0.y,w0.z,w0.w,w1.x,w1.y,w1.z,w1.w};
#pragma unroll
    for (int i=0;i<8;i++){
      acc[i].x = fmaf(wv[i], v.x, acc[i].x);
      acc[i].y = fmaf(wv[i], v.y, acc[i].y);
      acc[i].z = fmaf(wv[i], v.z, acc[i].z);
      acc[i].w = fmaf(wv[i], v.w, acc[i].w);
    }
  }
  float* ob = out + (size_t)b*CC*AREA_ + p0 + px;
#pragma unroll
  for (int i=0;i<8;i++)
    *(float4*)&ob[(size_t)(og*8+i)*AREA_] = acc[i];
}

// ---------- BN ----------
__global__ __launch_bounds__(256) void bn_part_kernel(const float* __restrict__ src,
    float* __restrict__ part){
  int c = blockIdx.x, chunk = blockIdx.y;
  float s1=0.f, s2=0.f;
  for (int b=0;b<BB;b++){
    const float* p = src + ((size_t)b*CC + c)*AREA_ + chunk*2048;
    for (int i=threadIdx.x;i<2048;i+=256){ float v=p[i]; s1+=v; s2+=v*v; }
  }
  __shared__ float red[8];
  float w1 = warp_rsum(s1), w2 = warp_rsum(s2);
  int lane = threadIdx.x & 63, wid = threadIdx.x >> 6;
  if (lane==0){ red[wid]=w1; red[4+wid]=w2; }
  __syncthreads();
  if (threadIdx.x==0){
    atomicAdd(&part[c], red[0]+red[1]+red[2]+red[3]);
    atomicAdd(&part[64+c], red[4]+red[5]+red[6]+red[7]);
  }
}

__global__ void bn_fin_kernel(const float* __restrict__ part, const float* __restrict__ gam,
    const float* __restrict__ bet, float* __restrict__ sb){
  int c = threadIdx.x;
  const float N = (float)(BB*AREA_);
  float m = part[c]/N;
  float var = part[64+c]/N - m*m;
  float sc = gam[c]*rsqrtf(var + 1e-5f);
  sb[c] = sc;
  sb[64+c] = bet[c] - m*sc;
}

__global__ __launch_bounds__(256) void bn_apply_relu_kernel(const float* __restrict__ src,
    const float* __restrict__ sb, float* __restrict__ dst){
  size_t i = (size_t)blockIdx.x*256 + threadIdx.x;
  int c = (int)((i >> 14) & 63);
  float v = fmaf(src[i], sb[c], sb[64+c]);
  dst[i] = v > 0.f ? v : 0.f;
}

// ---------- query conv ----------
__global__ __launch_bounds__(256) void qq_kernel(const float* __restrict__ y,
    const float* __restrict__ qw, float* __restrict__ qq){
  int blk = blockIdx.x;
  int p0 = (blk & 127) << 7;
  int s = (blk >> 7) & 1;
  int b = blk >> 8;
  __shared__ float tile[32][132];
  __shared__ float wsm[32][36];
  const float* qws = qw + s*HCC*HCC;
  for (int idx=threadIdx.x; idx<1024; idx+=256){
    int c = idx & 31, o = idx >> 5;
    wsm[c][o] = qws[o*32 + c];
  }
  const float* yb = y + ((size_t)b*CC + s*HCC)*AREA_ + p0;
  for (int idx=threadIdx.x; idx<4096; idx+=256){
    int c=idx>>7, pp=idx&127;
    tile[c][pp] = yb[(size_t)c*AREA_ + pp];
  }
  __syncthreads();
  int px = (threadIdx.x & 31) * 4;
  int og = threadIdx.x >> 5;
  float4 acc[4];
#pragma unroll
  for (int i=0;i<4;i++) acc[i] = make_float4(0.f,0.f,0.f,0.f);
  for (int c=0;c<32;c++){
    float4 v  = *(const float4*)&tile[c][px];
    float4 w0 = *(const float4*)&wsm[c][og*4];
    float wv[4] = {w0.x,w0.y,w0.z,w0.w};
#pragma unroll
    for (int i=0;i<4;i++){
      acc[i].x = fmaf(wv[i], v.x, acc[i].x);
      acc[i].y = fmaf(wv[i], v.y, acc[i].y);
      acc[i].z = fmaf(wv[i], v.z, acc[i].z);
      acc[i].w = fmaf(wv[i], v.w, acc[i].w);
    }
  }
  float* ob = qq + ((size_t)(b*SS+s)*HCC)*AREA_ + p0 + px;
#pragma unroll
  for (int i=0;i<4;i++)
    *(float4*)&ob[(size_t)(og*4+i)*AREA_] = acc[i];
}

// ---------- MFMA gram: stage one 8-elem unit of one U row into swizzled fp16 LDS ----------
__device__ __forceinline__ void stage_unit(_Float16* lds, const float* __restrict__ yb,
    const float* __restrict__ qqb, int pan, int pr, int u, int w, int h0, int dil){
  int kk = u*8;
  float v[8];
  if (pan < 2){
    const int offy[8] = {-1,-1,-1,0,1,1,1,0};
    const int offx[8] = {-1,0,1,1,1,0,-1,-1};
    int l = pan*4 + (pr>>5), ch = pr & 31;
    int oy = offy[l], ox = offx[l];
    const float* crow = yb + (size_t)ch*AREA_ + w*128 + h0 + kk;
    float4 c0 = *(const float4*)crow;
    float4 c1 = *(const float4*)(crow+4);
    float cen[8] = {c0.x,c0.y,c0.z,c0.w,c1.x,c1.y,c1.z,c1.w};
    float nb[8];
    int wy = w + oy*dil;
    if (wy >= 0 && wy < 128){
      int oxd = ox*dil;
      const float* nrow = yb + (size_t)ch*AREA_ + wy*128 + h0 + kk + oxd;
      float4 n0, n1;
      __builtin_memcpy(&n0, nrow, 16);
      __builtin_memcpy(&n1, nrow+4, 16);
      float nn[8] = {n0.x,n0.y,n0.z,n0.w,n1.x,n1.y,n1.z,n1.w};
      int hbase = h0 + kk + oxd;
#pragma unroll
      for (int j=0;j<8;j++){
        int hx = hbase + j;
        nb[j] = (hx>=0 && hx<128) ? nn[j] : 0.f;
      }
    } else {
#pragma unroll
      for (int j=0;j<8;j++) nb[j]=0.f;
    }
#pragma unroll
    for (int j=0;j<8;j++) v[j] = cen[j]-nb[j];
  } else {
    const float* src = (pr < 32) ? (yb + (size_t)pr*AREA_) : (qqb + (size_t)(pr-32)*AREA_);
    const float* crow = src + w*128 + h0 + kk;
    float4 c0 = *(const float4*)crow;
    float4 c1 = *(const float4*)(crow+4);
    v[0]=c0.x; v[1]=c0.y; v[2]=c0.z; v[3]=c0.w; v[4]=c1.x; v[5]=c1.y; v[6]=c1.z; v[7]=c1.w;
  }
  half8 hv;
#pragma unroll
  for (int j=0;j<8;j++) hv[j] = (_Float16)v[j];
  *(half8*)(lds + (size_t)pr*64 + ((u ^ (pr&7))<<3)) = hv;
}

// ---------- MFMA gram kernel ----------
__global__ __launch_bounds__(256,3) void gram_kernel(const float* __restrict__ y,
    const float* __restrict__ qq, float* __restrict__ dpart, float* __restrict__ wpart){
  const int PAarr[6]={0,0,1,0,1,2}, PBarr[6]={0,1,1,2,2,2};
  int slot = blockIdx.x, bs = blockIdx.y;
  int pair, Kstart, nch;
  if (slot < 48){ pair = slot>>4; Kstart = (slot&15)<<10; nch=16; }
  else if (slot < 64){ pair = 3 + ((slot-48)>>3); Kstart = ((slot-48)&7)<<11; nch=32; }
  else { pair=5; Kstart = (slot-64)<<12; nch=64; }
  int PA = PAarr[pair], PB = PBarr[pair];
  int RA = PA<2?128:64, CB = PB<2?128:64;
  bool diag = (PA==PB);
  int RB = diag?0:CB;
  int rows_tot = RA+RB;
  int s = bs & 1, b = bs >> 1, dil = 1+s;
  const float* yb = y + ((size_t)b*CC + s*HCC)*AREA_;
  const float* qqb = qq + (size_t)bs*HCC*AREA_;
  __shared__ __align__(16) _Float16 Asm[128*64];
  __shared__ __align__(16) _Float16 Bsm[128*64];
  int tid = threadIdx.x;
  int tsh = (rows_tot==64)?2:((rows_tot==128)?1:0);
  int rid = tid >> tsh, sub = tid & ((1<<tsh)-1);
  int un = 8 >> tsh, us0 = sub*un;
  bool do_stage = rid < rows_tot;
  int span = (rid < RA)? PA : PB;
  int spr  = (rid < RA)? rid : rid-RA;
  _Float16* slds = (rid < RA)? Asm : Bsm;
  int lane = tid & 63, wid = tid >> 6;
  int rbase = (wid>>1)*64, cbase = (wid&1)*64;
  bool active = (rbase < RA) && (cbase < CB);
  const _Float16* Ac = Asm;
  const _Float16* Bc = diag ? Asm : Bsm;
  f32x16 acc00={}, acc01={}, acc10={}, acc11={};
  int r0 = rbase + (lane&31), r1 = r0+32;
  int c0 = cbase + (lane&31), c1 = c0+32;
  int uo = lane>>5;
  for (int ch=0; ch<nch; ++ch){
    int k0 = Kstart + ch*64;
    int w = k0>>7, h0 = k0&127;
    if (do_stage){
      for (int u=us0; u<us0+un; ++u)
        stage_unit(slds, yb, qqb, span, spr, u, w, h0, dil);
    }
    __syncthreads();
    if (active){
#pragma unroll
      for (int st=0; st<4; ++st){
        int u = st*2 + uo;
        half8 a0 = *(const half8*)(Ac + (size_t)r0*64 + ((u^(r0&7))<<3));
        half8 a1 = *(const half8*)(Ac + (size_t)r1*64 + ((u^(r1&7))<<3));
        half8 b0 = *(const half8*)(Bc + (size_t)c0*64 + ((u^(c0&7))<<3));
        half8 b1 = *(const half8*)(Bc + (size_t)c1*64 + ((u^(c1&7))<<3));
        acc00 = __builtin_amdgcn_mfma_f32_32x32x16_f16(a0,b0,acc00,0,0,0);
        acc01 = __builtin_amdgcn_mfma_f32_32x32x16_f16(a0,b1,acc01,0,0,0);
        acc10 = __builtin_amdgcn_mfma_f32_32x32x16_f16(a1,b0,acc10,0,0,0);
        acc11 = __builtin_amdgcn_mfma_f32_32x32x16_f16(a1,b1,acc11,0,0,0);
      }
    }
    __syncthreads();
  }
  if (active){
    int gid = bs*68 + slot;
    float* pp = (gid<256)? dpart + (size_t)gid*16384 : wpart + (size_t)(gid-256)*16384;
    int rr = 4*(lane>>5), cc = lane&31;
#pragma unroll
    for (int reg=0;reg<16;reg++){
      int ro = (reg&3) + 8*(reg>>2) + rr;
      pp[(size_t)(rbase+ro)*128 + cbase+cc]       = acc00[reg];
      pp[(size_t)(rbase+ro)*128 + cbase+32+cc]    = acc01[reg];
      pp[(size_t)(rbase+32+ro)*128 + cbase+cc]    = acc10[reg];
      pp[(size_t)(rbase+32+ro)*128 + cbase+32+cc] = acc11[reg];
    }
  }
}

// ---------- reduce partials -> P (both triangles) ----------
__global__ __launch_bounds__(256) void reduce_kernel(const float* __restrict__ dpart,
    const float* __restrict__ wpart, float* __restrict__ P){
  const int PAarr[6]={0,0,1,0,1,2}, PBarr[6]={0,1,1,2,2,2};
  const int slotbase[6]={0,16,32,48,56,64}, nkarr[6]={16,16,16,8,8,4};
  int pair = blockIdx.x, bs = blockIdx.y;
  int PA = PAarr[pair], PB = PBarr[pair];
  int RN = PA<2?128:64, CN = PB<2?128:64;
  int Roff = PA*128, Coff = PB*128;
  int nk = nkarr[pair], sb0 = slotbase[pair];
  int csh = (CN==128)?7:6;
  float* Pb = P + (size_t)bs*102400;
  int cells = RN*CN;
  for (int cell = threadIdx.x; cell < cells; cell += 256){
    int r = cell >> csh, c = cell & (CN-1);
    float v = 0.f;
    for (int k=0;k<nk;k++){
      int gid = bs*68 + sb0 + k;
      const float* pp = (gid<256)? dpart + (size_t)gid*16384 : wpart + (size_t)(gid-256)*16384;
      v += pp[(size_t)r*128 + c];
    }
    Pb[(size_t)(Roff+r)*320 + Coff+c] = v;
    Pb[(size_t)(Coff+c)*320 + Roff+r] = v;
  }
}

// ---------- kw transpose ----------
__global__ __launch_bounds__(256) void kwT_kernel(const float* __restrict__ kw, float* __restrict__ kwT){
  int idx = blockIdx.x*256 + threadIdx.x;
  if (idx >= 2*KDIM*KDIM) return;
  int s = idx / (KDIM*KDIM);
  int r = idx - s*KDIM*KDIM;
  int k = r / KDIM, j = r - k*KDIM;
  kwT[(size_t)s*KDIM*KDIM + (size_t)j*KDIM + k] = kw[idx];
}

// ---------- V[j][k] = sum_jp P[j][jp] * kw[k][jp] ----------
__global__ __launch_bounds__(256) void vmat_kernel(const float* __restrict__ P,
    const float* __restrict__ kwT, float* __restrict__ V){
  int j = blockIdx.x, bs = blockIdx.y;
  int s = bs & 1;
  __shared__ float prow[KDIM];
  const float* Pb = P + (size_t)bs*102400 + (size_t)j*320;
  for (int i=threadIdx.x;i<KDIM;i+=256) prow[i]=Pb[i];
  __syncthreads();
  const float* kt = kwT + (size_t)s*KDIM*KDIM;
  int k = threadIdx.x;
  float acc=0.f;
  for (int jp=0;jp<KDIM;jp++) acc = fmaf(prow[jp], kt[(size_t)jp*KDIM + k], acc);
  V[((size_t)bs*KDIM + j)*256 + k] = acc;
}

// ---------- norms (reciprocal) ----------
__global__ void knorm_kernel(const float* __restrict__ P, const float* __restrict__ V,
    const float* __restrict__ kwT, float* __restrict__ nrm){
  int bs = blockIdx.x, s = bs & 1;
  int k = threadIdx.x;
  const float* Vb = V + (size_t)bs*KDIM*256;
  const float* kt = kwT + (size_t)s*KDIM*KDIM;
  float acc=0.f;
  for (int j=0;j<KDIM;j++) acc = fmaf(kt[(size_t)j*KDIM + k], Vb[(size_t)j*256 + k], acc);
  nrm[bs*KDIM + k] = 1.f/fmaxf(sqrtf(fmaxf(acc,0.f)), 1e-12f);
  if (k < 32){
    const float* Pb = P + (size_t)bs*102400;
    float q = Pb[(size_t)(288+k)*320 + 288+k];
    nrm[bs*KDIM + 256 + k] = 1.f/fmaxf(sqrtf(fmaxf(q,0.f)), 1e-12f);
  }
}

// ---------- w row + inorm partial stats ----------
__global__ __launch_bounds__(256) void wmat_kernel(const float* __restrict__ P,
    const float* __restrict__ kwT, const float* __restrict__ nrm,
    float* __restrict__ wbuf, float* __restrict__ wstats){
  int bs = blockIdx.x >> 5, c = blockIdx.x & 31;
  int s = bs & 1;
  __shared__ float prow[KDIM];
  const float* Pb = P + (size_t)bs*102400 + (size_t)(288+c)*320;
  for (int i=threadIdx.x;i<KDIM;i+=256) prow[i]=Pb[i];
  __syncthreads();
  const float* kt = kwT + (size_t)s*KDIM*KDIM;
  int k = threadIdx.x;
  float acc=0.f;
  for (int j=0;j<KDIM;j++) acc = fmaf(prow[j], kt[(size_t)j*KDIM + k], acc);
  float wv = acc * nrm[bs*KDIM + 256 + c] * nrm[bs*KDIM + k] * (1.f/128.f);
  wbuf[((size_t)bs*32 + c)*256 + k] = wv;
  __shared__ float red[8];
  float r1 = warp_rsum(wv), r2 = warp_rsum(wv*wv);
  int lane = threadIdx.x & 63, wid = threadIdx.x >> 6;
  if (lane==0){ red[wid]=r1; red[4+wid]=r2; }
  __syncthreads();
  if (threadIdx.x==0){
    atomicAdd(&wstats[bs*2],   red[0]+red[1]+red[2]+red[3]);
    atomicAdd(&wstats[bs*2+1], red[4]+red[5]+red[6]+red[7]);
  }
}

// ---------- inorm + softmax ----------
__global__ __launch_bounds__(256) void smx_kernel(const float* __restrict__ wbuf,
    const float* __restrict__ wstats, float* __restrict__ sw){
  int bs = blockIdx.x >> 5, c = blockIdx.x & 31;
  float s1 = wstats[bs*2], s2 = wstats[bs*2+1];
  const float N = 8192.f;
  float m = s1/N, var = s2/N - m*m;
  float rs = rsqrtf(var + 1e-5f);
  int k = threadIdx.x;
  float v = (wbuf[((size_t)bs*32 + c)*256 + k] - m)*rs;
  __shared__ float red[4];
  float mx = warp_rmax(v);
  int lane = k & 63, wid = k >> 6;
  if (lane==0) red[wid]=mx;
  __syncthreads();
  float MX = fmaxf(fmaxf(red[0],red[1]),fmaxf(red[2],red[3]));
  __syncthreads();
  float e = expf(v - MX);
  float es = warp_rsum(e);
  if (lane==0) red[wid]=es;
  __syncthreads();
  float ES = red[0]+red[1]+red[2]+red[3];
  sw[((size_t)bs*32 + c)*256 + k] = e/ES;
}

// ---------- tap coefficients ----------
__global__ __launch_bounds__(256) void tsw_kernel(const float* __restrict__ sw, float* __restrict__ tsw){
  int idx = blockIdx.x*256 + threadIdx.x;
  if (idx >= BB*SS*32*9*32) return;
  int ch = idx & 31;
  int t = (idx >> 5) % 9;
  int c = (idx / 288) & 31;
  int bs = idx / 9216;
  const float* swb = sw + ((size_t)bs*32 + c)*256;
  float v;
  if (t==0){ v=0.f; for (int l=0;l<8;l++) v += swb[l*32+ch]; }
  else v = -swb[(t-1)*32 + ch];
  tsw[idx] = v;
}

// ---------- attention as 9-tap stencil ----------
__global__ __launch_bounds__(256) void attn_apply_kernel(const float* __restrict__ y,
    const float* __restrict__ tsw, float* __restrict__ outs){
  int blk = blockIdx.x;
  int w = blk & 127;
  int s = (blk >> 7) & 1;
  int b = blk >> 8;
  int dil = 1 + s;
  __shared__ float T[9216];
  const float* tb = tsw + (size_t)(b*SS+s)*9216;
  for (int i=threadIdx.x;i<9216;i+=256) T[i]=tb[i];
  __syncthreads();
  int h = threadIdx.x & 127, cg = threadIdx.x >> 7;
  const float* yb = y + ((size_t)b*CC + s*HCC)*AREA_;
  float acc[16];
#pragma unroll
  for (int i=0;i<16;i++) acc[i]=0.f;
  const int offy[9]={0,-1,-1,-1,0,1,1,1,0};
  const int offx[9]={0,-1,0,1,1,1,0,-1,-1};
#pragma unroll
  for (int t=0;t<9;t++){
    int wy = w + offy[t]*dil;
    if (wy < 0 || wy >= 128) continue;
    int hx = h + offx[t]*dil;
    bool okh = (hx>=0 && hx<128);
    const float* ycol = yb + (size_t)wy*128 + hx;
    for (int c4=0;c4<8;c4++){
      float v0 = okh ? ycol[(size_t)(c4*4+0)*AREA_] : 0.f;
      float v1 = okh ? ycol[(size_t)(c4*4+1)*AREA_] : 0.f;
      float v2 = okh ? ycol[(size_t)(c4*4+2)*AREA_] : 0.f;
      float v3 = okh ? ycol[(size_t)(c4*4+3)*AREA_] : 0.f;
      const float* Tp = &T[(cg*16)*288 + t*32 + c4*4];
#pragma unroll
      for (int i=0;i<16;i++){
        float4 tw = *(const float4*)&Tp[(size_t)i*288];
        acc[i] = fmaf(tw.x, v0, fmaf(tw.y, v1, fmaf(tw.z, v2, fmaf(tw.w, v3, acc[i]))));
      }
    }
  }
  float* ob = outs + ((size_t)(b*SS+s)*HCC + cg*16)*AREA_ + (size_t)w*128 + h;
#pragma unroll
  for (int i=0;i<16;i++) ob[(size_t)i*AREA_] = acc[i];
}

extern "C" void kernel_launch(void* const* d_in, const int* in_sizes, int n_in,
                              void* d_out, int out_size, void* d_ws, size_t ws_size,
                              hipStream_t stream){
  const float* x   = (const float*)d_in[0];
  const float* tw  = (const float*)d_in[1];
  const float* g1  = (const float*)d_in[2];
  const float* b1  = (const float*)d_in[3];
  const float* qw  = (const float*)d_in[4];
  const float* kw  = (const float*)d_in[5];
  const float* ow  = (const float*)d_in[6];
  const float* g2  = (const float*)d_in[7];
  const float* b2  = (const float*)d_in[8];
  float* out = (float*)d_out;
  float* ws = (float*)d_ws;

  // Workspace layout (floats; all live ranges disjoint, verified):
  //   [0,64)                pad for edge-neighbor reads below y
  //   y      @ 64           .. 4,194,368   (4,194,304)
  //   qqb    @ 4,194,368    .. 8,388,672   (4,194,304)  [dead after gram]
  //     kwT  @ 4,194,368    .. 4,360,256   (165,888; alias, after gram)
  //     wbuf @ 4,360,256    .. 4,425,792   (65,536;  alias, after gram)
  //   wpart  @ 8,388,672    .. 13,107,264  (4,718,592) [dead after reduce]
  //     outs @ 8,388,672    .. 12,582,976  (alias, after reduce)
  //   P      @ 13,107,264   .. 13,926,464  (819,200)
  //   stats  @ 13,926,464   (256)   wstats @ 13,926,720 (16; memset w/ stats)
  //   sb     @ 13,926,976   (256)
  //   swb    @ 13,927,232   .. 13,992,768  (65,536)
  //   tswb   @ 13,992,768   .. 14,066,496  (73,728)
  //   nrm    @ 14,066,496   .. 14,068,800  (2,304)
  // d_out (4,194,304 = out_size): dpart (256 gram slots), then V (589,824),
  //   both dead before the final bn_apply_relu writes `out`.
  float* y      = ws + 64;
  float* qqb    = ws + 4194368;
  float* kwT    = qqb;
  float* wbuf   = ws + 4360256;
  float* wpart  = ws + 8388672;
  float* outs   = wpart;
  float* P      = ws + 13107264;
  float* stats  = ws + 13926464;
  float* wstats = ws + 13926720;
  float* sb     = ws + 13926976;
  float* swb    = ws + 13927232;
  float* tswb   = ws + 13992768;
  float* nrm    = ws + 14066496;
  float* dpart  = (float*)d_out;
  float* V      = (float*)d_out;
  float* z      = y;

  hipMemsetAsync(stats, 0, 512*sizeof(float), stream);

  conv64_kernel<<<512,256,0,stream>>>(x, tw, y);
  bn_part_kernel<<<dim3(64,8),256,0,stream>>>(y, stats);
  bn_fin_kernel<<<1,64,0,stream>>>(stats, g1, b1, sb);
  bn_apply_relu_kernel<<<16384,256,0,stream>>>(y, sb, y);
  qq_kernel<<<1024,256,0,stream>>>(y, qw, qqb);
  gram_kernel<<<dim3(68,8),256,0,stream>>>(y, qqb, dpart, wpart);
  reduce_kernel<<<dim3(6,8),256,0,stream>>>(dpart, wpart, P);
  kwT_kernel<<<648,256,0,stream>>>(kw, kwT);
  vmat_kernel<<<dim3(288,8),256,0,stream>>>(P, kwT, V);
  knorm_kernel<<<8,256,0,stream>>>(P, V, kwT, nrm);
  wmat_kernel<<<256,256,0,stream>>>(P, kwT, nrm, wbuf, wstats);
  smx_kernel<<<256,256,0,stream>>>(wbuf, wstats, swb);
  tsw_kernel<<<288,256,0,stream>>>(swb, tswb);
  attn_apply_kernel<<<1024,256,0,stream>>>(y, tswb, outs);
  conv64_kernel<<<512,256,0,stream>>>(outs, ow, z);
  bn_part_kernel<<<dim3(64,8),256,0,stream>>>(z, stats+128);
  bn_fin_kernel<<<1,64,0,stream>>>(stats+128, g2, b2, sb+128);
  bn_apply_relu_kernel<<<16384,256,0,stream>>>(z, sb+128, out);
}

// Round 5
// 494.201 us; speedup vs baseline: 5.2434x; 1.5856x over previous
//
#include <hip/hip_runtime.h>

#define BB 4
#define CC 64
#define SS 2
#define HCC 32
#define AREA_ 16384
#define KDIM 288

typedef _Float16 half8 __attribute__((ext_vector_type(8)));
typedef float f32x16 __attribute__((ext_vector_type(16)));

static __device__ __forceinline__ float warp_rsum(float v){
#pragma unroll
  for (int o=32;o>0;o>>=1) v += __shfl_down(v,o,64);
  return v;
}
static __device__ __forceinline__ float warp_rmax(float v){
#pragma unroll
  for (int o=32;o>0;o>>=1) v = fmaxf(v,__shfl_down(v,o,64));
  return v;
}

// ---------- 64x64 1x1 conv ----------
__global__ __launch_bounds__(256) void conv64_kernel(const float* __restrict__ in,
    const float* __restrict__ wmat, float* __restrict__ out){
  int b = blockIdx.x >> 7;
  int p0 = (blockIdx.x & 127) << 7;
  __shared__ float tile[64][132];
  __shared__ float wsm[64][68];
  for (int idx = threadIdx.x; idx < 4096; idx += 256){
    int c = idx & 63, o = idx >> 6;
    wsm[c][o] = wmat[o*64 + c];
  }
  const float* inb = in + (size_t)b*CC*AREA_ + p0;
  for (int idx = threadIdx.x; idx < 8192; idx += 256){
    int c = idx >> 7, pp = idx & 127;
    tile[c][pp] = inb[(size_t)c*AREA_ + pp];
  }
  __syncthreads();
  int px = (threadIdx.x & 31) * 4;
  int og = threadIdx.x >> 5;
  float4 acc[8];
#pragma unroll
  for (int i=0;i<8;i++) acc[i] = make_float4(0.f,0.f,0.f,0.f);
  for (int c=0;c<64;c++){
    float4 v  = *(const float4*)&tile[c][px];
    float4 w0 = *(const float4*)&wsm[c][og*8];
    float4 w1 = *(const float4*)&wsm[c][og*8+4];
    float wv[8] = {w0.x,w0.y,w0.z,w0.w,w1.x,w1.y,w1.z,w1.w};
#pragma unroll
    for (int i=0;i<8;i++){
      acc[i].x = fmaf(wv[i], v.x, acc[i].x);
      acc[i].y = fmaf(wv[i], v.y, acc[i].y);
      acc[i].z = fmaf(wv[i], v.z, acc[i].z);
      acc[i].w = fmaf(wv[i], v.w, acc[i].w);
    }
  }
  float* ob = out + (size_t)b*CC*AREA_ + p0 + px;
#pragma unroll
  for (int i=0;i<8;i++)
    *(float4*)&ob[(size_t)(og*8+i)*AREA_] = acc[i];
}

// ---------- BN ----------
__global__ __launch_bounds__(256) void bn_part_kernel(const float* __restrict__ src,
    float* __restrict__ part){
  int c = blockIdx.x, chunk = blockIdx.y;
  float s1=0.f, s2=0.f;
  for (int b=0;b<BB;b++){
    const float* p = src + ((size_t)b*CC + c)*AREA_ + chunk*2048;
    for (int i=threadIdx.x;i<2048;i+=256){ float v=p[i]; s1+=v; s2+=v*v; }
  }
  __shared__ float red[8];
  float w1 = warp_rsum(s1), w2 = warp_rsum(s2);
  int lane = threadIdx.x & 63, wid = threadIdx.x >> 6;
  if (lane==0){ red[wid]=w1; red[4+wid]=w2; }
  __syncthreads();
  if (threadIdx.x==0){
    atomicAdd(&part[c], red[0]+red[1]+red[2]+red[3]);
    atomicAdd(&part[64+c], red[4]+red[5]+red[6]+red[7]);
  }
}

__global__ void bn_fin_kernel(const float* __restrict__ part, const float* __restrict__ gam,
    const float* __restrict__ bet, float* __restrict__ sb){
  int c = threadIdx.x;
  const float N = (float)(BB*AREA_);
  float m = part[c]/N;
  float var = part[64+c]/N - m*m;
  float sc = gam[c]*rsqrtf(var + 1e-5f);
  sb[c] = sc;
  sb[64+c] = bet[c] - m*sc;
}

__global__ __launch_bounds__(256) void bn_apply_relu_kernel(const float* __restrict__ src,
    const float* __restrict__ sb, float* __restrict__ dst){
  size_t i = (size_t)blockIdx.x*256 + threadIdx.x;
  int c = (int)((i >> 14) & 63);
  float v = fmaf(src[i], sb[c], sb[64+c]);
  dst[i] = v > 0.f ? v : 0.f;
}

// ---------- query conv ----------
__global__ __launch_bounds__(256) void qq_kernel(const float* __restrict__ y,
    const float* __restrict__ qw, float* __restrict__ qq){
  int blk = blockIdx.x;
  int p0 = (blk & 127) << 7;
  int s = (blk >> 7) & 1;
  int b = blk >> 8;
  __shared__ float tile[32][132];
  __shared__ float wsm[32][36];
  const float* qws = qw + s*HCC*HCC;
  for (int idx=threadIdx.x; idx<1024; idx+=256){
    int c = idx & 31, o = idx >> 5;
    wsm[c][o] = qws[o*32 + c];
  }
  const float* yb = y + ((size_t)b*CC + s*HCC)*AREA_ + p0;
  for (int idx=threadIdx.x; idx<4096; idx+=256){
    int c=idx>>7, pp=idx&127;
    tile[c][pp] = yb[(size_t)c*AREA_ + pp];
  }
  __syncthreads();
  int px = (threadIdx.x & 31) * 4;
  int og = threadIdx.x >> 5;
  float4 acc[4];
#pragma unroll
  for (int i=0;i<4;i++) acc[i] = make_float4(0.f,0.f,0.f,0.f);
  for (int c=0;c<32;c++){
    float4 v  = *(const float4*)&tile[c][px];
    float4 w0 = *(const float4*)&wsm[c][og*4];
    float wv[4] = {w0.x,w0.y,w0.z,w0.w};
#pragma unroll
    for (int i=0;i<4;i++){
      acc[i].x = fmaf(wv[i], v.x, acc[i].x);
      acc[i].y = fmaf(wv[i], v.y, acc[i].y);
      acc[i].z = fmaf(wv[i], v.z, acc[i].z);
      acc[i].w = fmaf(wv[i], v.w, acc[i].w);
    }
  }
  float* ob = qq + ((size_t)(b*SS+s)*HCC)*AREA_ + p0 + px;
#pragma unroll
  for (int i=0;i<4;i++)
    *(float4*)&ob[(size_t)(og*4+i)*AREA_] = acc[i];
}

// ---------- MFMA gram: stage one 8-elem unit of one U row into swizzled fp16 LDS ----------
__device__ __forceinline__ void stage_unit(_Float16* lds, const float* __restrict__ yb,
    const float* __restrict__ qqb, int pan, int pr, int u, int w, int h0, int dil){
  int kk = u*8;
  float v[8];
  if (pan < 2){
    const int offy[8] = {-1,-1,-1,0,1,1,1,0};
    const int offx[8] = {-1,0,1,1,1,0,-1,-1};
    int l = pan*4 + (pr>>5), ch = pr & 31;
    int oy = offy[l], ox = offx[l];
    const float* crow = yb + (size_t)ch*AREA_ + w*128 + h0 + kk;
    float4 c0 = *(const float4*)crow;
    float4 c1 = *(const float4*)(crow+4);
    float cen[8] = {c0.x,c0.y,c0.z,c0.w,c1.x,c1.y,c1.z,c1.w};
    float nb[8];
    int wy = w + oy*dil;
    if (wy >= 0 && wy < 128){
      int oxd = ox*dil;
      const float* nrow = yb + (size_t)ch*AREA_ + wy*128 + h0 + kk + oxd;
      float4 n0, n1;
      __builtin_memcpy(&n0, nrow, 16);
      __builtin_memcpy(&n1, nrow+4, 16);
      float nn[8] = {n0.x,n0.y,n0.z,n0.w,n1.x,n1.y,n1.z,n1.w};
      int hbase = h0 + kk + oxd;
#pragma unroll
      for (int j=0;j<8;j++){
        int hx = hbase + j;
        nb[j] = (hx>=0 && hx<128) ? nn[j] : 0.f;
      }
    } else {
#pragma unroll
      for (int j=0;j<8;j++) nb[j]=0.f;
    }
#pragma unroll
    for (int j=0;j<8;j++) v[j] = cen[j]-nb[j];
  } else {
    const float* src = (pr < 32) ? (yb + (size_t)pr*AREA_) : (qqb + (size_t)(pr-32)*AREA_);
    const float* crow = src + w*128 + h0 + kk;
    float4 c0 = *(const float4*)crow;
    float4 c1 = *(const float4*)(crow+4);
    v[0]=c0.x; v[1]=c0.y; v[2]=c0.z; v[3]=c0.w; v[4]=c1.x; v[5]=c1.y; v[6]=c1.z; v[7]=c1.w;
  }
  half8 hv;
#pragma unroll
  for (int j=0;j<8;j++) hv[j] = (_Float16)v[j];
  *(half8*)(lds + (size_t)pr*64 + ((u ^ (pr&7))<<3)) = hv;
}

// ---------- MFMA gram kernel ----------
__global__ __launch_bounds__(256,3) void gram_kernel(const float* __restrict__ y,
    const float* __restrict__ qq, float* __restrict__ dpart, float* __restrict__ wpart){
  const int PAarr[6]={0,0,1,0,1,2}, PBarr[6]={0,1,1,2,2,2};
  int slot = blockIdx.x, bs = blockIdx.y;
  int pair, Kstart, nch;
  if (slot < 48){ pair = slot>>4; Kstart = (slot&15)<<10; nch=16; }
  else if (slot < 64){ pair = 3 + ((slot-48)>>3); Kstart = ((slot-48)&7)<<11; nch=32; }
  else { pair=5; Kstart = (slot-64)<<12; nch=64; }
  int PA = PAarr[pair], PB = PBarr[pair];
  int RA = PA<2?128:64, CB = PB<2?128:64;
  bool diag = (PA==PB);
  int RB = diag?0:CB;
  int rows_tot = RA+RB;
  int s = bs & 1, b = bs >> 1, dil = 1+s;
  const float* yb = y + ((size_t)b*CC + s*HCC)*AREA_;
  const float* qqb = qq + (size_t)bs*HCC*AREA_;
  __shared__ __align__(16) _Float16 Asm[128*64];
  __shared__ __align__(16) _Float16 Bsm[128*64];
  int tid = threadIdx.x;
  int tsh = (rows_tot==64)?2:((rows_tot==128)?1:0);
  int rid = tid >> tsh, sub = tid & ((1<<tsh)-1);
  int un = 8 >> tsh, us0 = sub*un;
  bool do_stage = rid < rows_tot;
  int span = (rid < RA)? PA : PB;
  int spr  = (rid < RA)? rid : rid-RA;
  _Float16* slds = (rid < RA)? Asm : Bsm;
  int lane = tid & 63, wid = tid >> 6;
  int rbase = (wid>>1)*64, cbase = (wid&1)*64;
  bool active = (rbase < RA) && (cbase < CB);
  const _Float16* Ac = Asm;
  const _Float16* Bc = diag ? Asm : Bsm;
  f32x16 acc00={}, acc01={}, acc10={}, acc11={};
  int r0 = rbase + (lane&31), r1 = r0+32;
  int c0 = cbase + (lane&31), c1 = c0+32;
  int uo = lane>>5;
  for (int ch=0; ch<nch; ++ch){
    int k0 = Kstart + ch*64;
    int w = k0>>7, h0 = k0&127;
    if (do_stage){
      for (int u=us0; u<us0+un; ++u)
        stage_unit(slds, yb, qqb, span, spr, u, w, h0, dil);
    }
    __syncthreads();
    if (active){
#pragma unroll
      for (int st=0; st<4; ++st){
        int u = st*2 + uo;
        half8 a0 = *(const half8*)(Ac + (size_t)r0*64 + ((u^(r0&7))<<3));
        half8 a1 = *(const half8*)(Ac + (size_t)r1*64 + ((u^(r1&7))<<3));
        half8 b0 = *(const half8*)(Bc + (size_t)c0*64 + ((u^(c0&7))<<3));
        half8 b1 = *(const half8*)(Bc + (size_t)c1*64 + ((u^(c1&7))<<3));
        acc00 = __builtin_amdgcn_mfma_f32_32x32x16_f16(a0,b0,acc00,0,0,0);
        acc01 = __builtin_amdgcn_mfma_f32_32x32x16_f16(a0,b1,acc01,0,0,0);
        acc10 = __builtin_amdgcn_mfma_f32_32x32x16_f16(a1,b0,acc10,0,0,0);
        acc11 = __builtin_amdgcn_mfma_f32_32x32x16_f16(a1,b1,acc11,0,0,0);
      }
    }
    __syncthreads();
  }
  if (active){
    int gid = bs*68 + slot;
    float* pp = (gid<256)? dpart + (size_t)gid*16384 : wpart + (size_t)(gid-256)*16384;
    int rr = 4*(lane>>5), cc = lane&31;
#pragma unroll
    for (int reg=0;reg<16;reg++){
      int ro = (reg&3) + 8*(reg>>2) + rr;
      pp[(size_t)(rbase+ro)*128 + cbase+cc]       = acc00[reg];
      pp[(size_t)(rbase+ro)*128 + cbase+32+cc]    = acc01[reg];
      pp[(size_t)(rbase+32+ro)*128 + cbase+cc]    = acc10[reg];
      pp[(size_t)(rbase+32+ro)*128 + cbase+32+cc] = acc11[reg];
    }
  }
}

// ---------- reduce partials -> P (both triangles), parallel ----------
// grid: (68 chunks, 8 bs); each block: 1024 cells of one pair, 4 cells/thread (float4)
__global__ __launch_bounds__(256) void reduce_kernel(const float* __restrict__ dpart,
    const float* __restrict__ wpart, float* __restrict__ P){
  const int PAarr[6]={0,0,1,0,1,2}, PBarr[6]={0,1,1,2,2,2};
  const int slotbase[6]={0,16,32,48,56,64}, nkarr[6]={16,16,16,8,8,4};
  const int chunkbase[7]={0,16,32,48,56,64,68};
  int chunk = blockIdx.x, bs = blockIdx.y;
  int pair = 0;
  while (chunk >= chunkbase[pair+1]) pair++;
  int lc = chunk - chunkbase[pair];
  int PA = PAarr[pair], PB = PBarr[pair];
  int CN = PB<2?128:64;
  int Roff = PA*128, Coff = PB*128;
  int nk = nkarr[pair], sb0 = slotbase[pair];
  int csh = (CN==128)?7:6;
  int cell0 = lc*1024 + threadIdx.x*4;
  int r = cell0 >> csh, c = cell0 & (CN-1);
  float4 v = make_float4(0.f,0.f,0.f,0.f);
  int gidb = bs*68 + sb0;
  for (int k=0;k<nk;k++){
    int gid = gidb + k;
    const float* pp = (gid<256)? dpart + (size_t)gid*16384 : wpart + (size_t)(gid-256)*16384;
    float4 t = *(const float4*)&pp[(size_t)r*128 + c];
    v.x += t.x; v.y += t.y; v.z += t.z; v.w += t.w;
  }
  float* Pb = P + (size_t)bs*102400;
  *(float4*)&Pb[(size_t)(Roff+r)*320 + Coff+c] = v;
  Pb[(size_t)(Coff+c  )*320 + Roff+r] = v.x;
  Pb[(size_t)(Coff+c+1)*320 + Roff+r] = v.y;
  Pb[(size_t)(Coff+c+2)*320 + Roff+r] = v.z;
  Pb[(size_t)(Coff+c+3)*320 + Roff+r] = v.w;
}

// ---------- kw transpose ----------
__global__ __launch_bounds__(256) void kwT_kernel(const float* __restrict__ kw, float* __restrict__ kwT){
  int idx = blockIdx.x*256 + threadIdx.x;
  if (idx >= 2*KDIM*KDIM) return;
  int s = idx / (KDIM*KDIM);
  int r = idx - s*KDIM*KDIM;
  int k = r / KDIM, j = r - k*KDIM;
  kwT[(size_t)s*KDIM*KDIM + (size_t)j*KDIM + k] = kw[idx];
}

// ---------- V[j][k] = sum_jp P[j][jp] * kw[k][jp] ----------
__global__ __launch_bounds__(256) void vmat_kernel(const float* __restrict__ P,
    const float* __restrict__ kwT, float* __restrict__ V){
  int j = blockIdx.x, bs = blockIdx.y;
  int s = bs & 1;
  __shared__ float prow[KDIM];
  const float* Pb = P + (size_t)bs*102400 + (size_t)j*320;
  for (int i=threadIdx.x;i<KDIM;i+=256) prow[i]=Pb[i];
  __syncthreads();
  const float* kt = kwT + (size_t)s*KDIM*KDIM;
  int k = threadIdx.x;
  float acc=0.f;
  for (int jp=0;jp<KDIM;jp++) acc = fmaf(prow[jp], kt[(size_t)jp*KDIM + k], acc);
  V[((size_t)bs*KDIM + j)*256 + k] = acc;
}

// ---------- norms (reciprocal) ----------
__global__ void knorm_kernel(const float* __restrict__ P, const float* __restrict__ V,
    const float* __restrict__ kwT, float* __restrict__ nrm){
  int bs = blockIdx.x, s = bs & 1;
  int k = threadIdx.x;
  const float* Vb = V + (size_t)bs*KDIM*256;
  const float* kt = kwT + (size_t)s*KDIM*KDIM;
  float acc=0.f;
  for (int j=0;j<KDIM;j++) acc = fmaf(kt[(size_t)j*KDIM + k], Vb[(size_t)j*256 + k], acc);
  nrm[bs*KDIM + k] = 1.f/fmaxf(sqrtf(fmaxf(acc,0.f)), 1e-12f);
  if (k < 32){
    const float* Pb = P + (size_t)bs*102400;
    float q = Pb[(size_t)(288+k)*320 + 288+k];
    nrm[bs*KDIM + 256 + k] = 1.f/fmaxf(sqrtf(fmaxf(q,0.f)), 1e-12f);
  }
}

// ---------- w row + inorm partial stats ----------
__global__ __launch_bounds__(256) void wmat_kernel(const float* __restrict__ P,
    const float* __restrict__ kwT, const float* __restrict__ nrm,
    float* __restrict__ wbuf, float* __restrict__ wstats){
  int bs = blockIdx.x >> 5, c = blockIdx.x & 31;
  int s = bs & 1;
  __shared__ float prow[KDIM];
  const float* Pb = P + (size_t)bs*102400 + (size_t)(288+c)*320;
  for (int i=threadIdx.x;i<KDIM;i+=256) prow[i]=Pb[i];
  __syncthreads();
  const float* kt = kwT + (size_t)s*KDIM*KDIM;
  int k = threadIdx.x;
  float acc=0.f;
  for (int j=0;j<KDIM;j++) acc = fmaf(prow[j], kt[(size_t)j*KDIM + k], acc);
  float wv = acc * nrm[bs*KDIM + 256 + c] * nrm[bs*KDIM + k] * (1.f/128.f);
  wbuf[((size_t)bs*32 + c)*256 + k] = wv;
  __shared__ float red[8];
  float r1 = warp_rsum(wv), r2 = warp_rsum(wv*wv);
  int lane = threadIdx.x & 63, wid = threadIdx.x >> 6;
  if (lane==0){ red[wid]=r1; red[4+wid]=r2; }
  __syncthreads();
  if (threadIdx.x==0){
    atomicAdd(&wstats[bs*2],   red[0]+red[1]+red[2]+red[3]);
    atomicAdd(&wstats[bs*2+1], red[4]+red[5]+red[6]+red[7]);
  }
}

// ---------- inorm + softmax ----------
__global__ __launch_bounds__(256) void smx_kernel(const float* __restrict__ wbuf,
    const float* __restrict__ wstats, float* __restrict__ sw){
  int bs = blockIdx.x >> 5, c = blockIdx.x & 31;
  float s1 = wstats[bs*2], s2 = wstats[bs*2+1];
  const float N = 8192.f;
  float m = s1/N, var = s2/N - m*m;
  float rs = rsqrtf(var + 1e-5f);
  int k = threadIdx.x;
  float v = (wbuf[((size_t)bs*32 + c)*256 + k] - m)*rs;
  __shared__ float red[4];
  float mx = warp_rmax(v);
  int lane = k & 63, wid = k >> 6;
  if (lane==0) red[wid]=mx;
  __syncthreads();
  float MX = fmaxf(fmaxf(red[0],red[1]),fmaxf(red[2],red[3]));
  __syncthreads();
  float e = expf(v - MX);
  float es = warp_rsum(e);
  if (lane==0) red[wid]=es;
  __syncthreads();
  float ES = red[0]+red[1]+red[2]+red[3];
  sw[((size_t)bs*32 + c)*256 + k] = e/ES;
}

// ---------- tap coefficients ----------
__global__ __launch_bounds__(256) void tsw_kernel(const float* __restrict__ sw, float* __restrict__ tsw){
  int idx = blockIdx.x*256 + threadIdx.x;
  if (idx >= BB*SS*32*9*32) return;
  int ch = idx & 31;
  int t = (idx >> 5) % 9;
  int c = (idx / 288) & 31;
  int bs = idx / 9216;
  const float* swb = sw + ((size_t)bs*32 + c)*256;
  float v;
  if (t==0){ v=0.f; for (int l=0;l<8;l++) v += swb[l*32+ch]; }
  else v = -swb[(t-1)*32 + ch];
  tsw[idx] = v;
}

// ---------- attention as 9-tap stencil ----------
__global__ __launch_bounds__(256) void attn_apply_kernel(const float* __restrict__ y,
    const float* __restrict__ tsw, float* __restrict__ outs){
  int blk = blockIdx.x;
  int w = blk & 127;
  int s = (blk >> 7) & 1;
  int b = blk >> 8;
  int dil = 1 + s;
  __shared__ float T[9216];
  const float* tb = tsw + (size_t)(b*SS+s)*9216;
  for (int i=threadIdx.x;i<9216;i+=256) T[i]=tb[i];
  __syncthreads();
  int h = threadIdx.x & 127, cg = threadIdx.x >> 7;
  const float* yb = y + ((size_t)b*CC + s*HCC)*AREA_;
  float acc[16];
#pragma unroll
  for (int i=0;i<16;i++) acc[i]=0.f;
  const int offy[9]={0,-1,-1,-1,0,1,1,1,0};
  const int offx[9]={0,-1,0,1,1,1,0,-1,-1};
#pragma unroll
  for (int t=0;t<9;t++){
    int wy = w + offy[t]*dil;
    if (wy < 0 || wy >= 128) continue;
    int hx = h + offx[t]*dil;
    bool okh = (hx>=0 && hx<128);
    const float* ycol = yb + (size_t)wy*128 + hx;
    for (int c4=0;c4<8;c4++){
      float v0 = okh ? ycol[(size_t)(c4*4+0)*AREA_] : 0.f;
      float v1 = okh ? ycol[(size_t)(c4*4+1)*AREA_] : 0.f;
      float v2 = okh ? ycol[(size_t)(c4*4+2)*AREA_] : 0.f;
      float v3 = okh ? ycol[(size_t)(c4*4+3)*AREA_] : 0.f;
      const float* Tp = &T[(cg*16)*288 + t*32 + c4*4];
#pragma unroll
      for (int i=0;i<16;i++){
        float4 tw = *(const float4*)&Tp[(size_t)i*288];
        acc[i] = fmaf(tw.x, v0, fmaf(tw.y, v1, fmaf(tw.z, v2, fmaf(tw.w, v3, acc[i]))));
      }
    }
  }
  float* ob = outs + ((size_t)(b*SS+s)*HCC + cg*16)*AREA_ + (size_t)w*128 + h;
#pragma unroll
  for (int i=0;i<16;i++) ob[(size_t)i*AREA_] = acc[i];
}

extern "C" void kernel_launch(void* const* d_in, const int* in_sizes, int n_in,
                              void* d_out, int out_size, void* d_ws, size_t ws_size,
                              hipStream_t stream){
  const float* x   = (const float*)d_in[0];
  const float* tw  = (const float*)d_in[1];
  const float* g1  = (const float*)d_in[2];
  const float* b1  = (const float*)d_in[3];
  const float* qw  = (const float*)d_in[4];
  const float* kw  = (const float*)d_in[5];
  const float* ow  = (const float*)d_in[6];
  const float* g2  = (const float*)d_in[7];
  const float* b2  = (const float*)d_in[8];
  float* out = (float*)d_out;
  float* ws = (float*)d_ws;

  // Workspace layout (floats; all live ranges disjoint):
  //   [0,64) pad | y@64 | qqb@4194368 (kwT/wbuf alias after gram)
  //   wpart@8388672 (outs alias after reduce) | P@13107264
  //   stats@13926464 wstats@13926720 sb@13926976 swb@13927232
  //   tswb@13992768 nrm@14066496
  // d_out: dpart (gram partials) then V; both dead before final BN write.
  float* y      = ws + 64;
  float* qqb    = ws + 4194368;
  float* kwT    = qqb;
  float* wbuf   = ws + 4360256;
  float* wpart  = ws + 8388672;
  float* outs   = wpart;
  float* P      = ws + 13107264;
  float* stats  = ws + 13926464;
  float* wstats = ws + 13926720;
  float* sb     = ws + 13926976;
  float* swb    = ws + 13927232;
  float* tswb   = ws + 13992768;
  float* nrm    = ws + 14066496;
  float* dpart  = (float*)d_out;
  float* V      = (float*)d_out;
  float* z      = y;

  hipMemsetAsync(stats, 0, 512*sizeof(float), stream);

  conv64_kernel<<<512,256,0,stream>>>(x, tw, y);
  bn_part_kernel<<<dim3(64,8),256,0,stream>>>(y, stats);
  bn_fin_kernel<<<1,64,0,stream>>>(stats, g1, b1, sb);
  bn_apply_relu_kernel<<<16384,256,0,stream>>>(y, sb, y);
  qq_kernel<<<1024,256,0,stream>>>(y, qw, qqb);
  gram_kernel<<<dim3(68,8),256,0,stream>>>(y, qqb, dpart, wpart);
  reduce_kernel<<<dim3(68,8),256,0,stream>>>(dpart, wpart, P);
  kwT_kernel<<<648,256,0,stream>>>(kw, kwT);
  vmat_kernel<<<dim3(288,8),256,0,stream>>>(P, kwT, V);
  knorm_kernel<<<8,256,0,stream>>>(P, V, kwT, nrm);
  wmat_kernel<<<256,256,0,stream>>>(P, kwT, nrm, wbuf, wstats);
  smx_kernel<<<256,256,0,stream>>>(wbuf, wstats, swb);
  tsw_kernel<<<288,256,0,stream>>>(swb, tswb);
  attn_apply_kernel<<<1024,256,0,stream>>>(y, tswb, outs);
  conv64_kernel<<<512,256,0,stream>>>(outs, ow, z);
  bn_part_kernel<<<dim3(64,8),256,0,stream>>>(z, stats+128);
  bn_fin_kernel<<<1,64,0,stream>>>(stats+128, g2, b2, sb+128);
  bn_apply_relu_kernel<<<16384,256,0,stream>>>(z, sb+128, out);
}